// Round 9
// baseline (99.701 us; speedup 1.0000x reference)
//
#include <hip/hip_runtime.h>

#define E_TOTAL 262144
#define TPB 256
#define NHBLK 1024            // hist/scatter blocks (256 pairs each)
#define NMBLK 1024            // mfma main blocks (4 waves each)
#define NT_MAX 16400          // max 16-pair tiles after per-type 16-alignment

typedef __attribute__((ext_vector_type(8))) short short8;
typedef __attribute__((ext_vector_type(4))) float f32x4;

__device__ __forceinline__ float silu_f(float x) {
    return x / (1.0f + __expf(-x));
}

// RNE float -> bf16 bits
__device__ __forceinline__ short f2bf(float f) {
    unsigned int u = __float_as_uint(f);
    u += 0x7fffu + ((u >> 16) & 1u);
    return (short)(u >> 16);
}

// ---- 1. per-block type histogram (deterministic, no atomics) ----
__global__ __launch_bounds__(TPB)
void nep_hist(const int* __restrict__ ij, int* __restrict__ counts)
{
    __shared__ unsigned char sty[TPB];
    const int tid = threadIdx.x, b = blockIdx.x;
    sty[tid] = (unsigned char)ij[b * TPB + tid];
    __syncthreads();
    if (tid < 16) {
        const uchar4* s4 = (const uchar4*)sty;
        int c = 0;
        #pragma unroll 8
        for (int j = 0; j < TPB / 4; j++) {
            uchar4 v = s4[j];
            c += (v.x == tid) + (v.y == tid) + (v.z == tid) + (v.w == tid);
        }
        counts[b * 16 + tid] = c;
    }
}

// ---- 2. single-block scan: segment offsets (16-aligned), pos_base, pads,
//         tile_type table, and W0/W1 fp32->bf16 pre-conversion ----
__global__ __launch_bounds__(1024)
void nep_scan(const int* __restrict__ counts, int* __restrict__ pos_base,
              int* __restrict__ tile_type, int* __restrict__ sorted_idx,
              const float* __restrict__ W0g, const float* __restrict__ W1g,
              short* __restrict__ W0bf, short* __restrict__ W1bf)
{
    __shared__ int tot[16];
    __shared__ int segoff[17];
    const int tid = threadIdx.x;
    const int w = tid >> 6;      // type handled by this wave
    const int l = tid & 63;

    // lane l covers blocks l, l+64, ... (lane-major enumeration; bijective)
    int pre[16];
    int s = 0;
    #pragma unroll
    for (int i = 0; i < 16; i++) {
        int b = l + 64 * i;
        int c = counts[b * 16 + w];
        pre[i] = s; s += c;
    }
    // wave-inclusive scan of per-lane totals
    int inc = s;
    #pragma unroll
    for (int off = 1; off < 64; off <<= 1) {
        int v = __shfl_up(inc, off, 64);
        if (l >= off) inc += v;
    }
    int lane_excl = inc - s;
    if (l == 63) tot[w] = inc;
    __syncthreads();
    if (tid == 0) {
        int acc = 0;
        #pragma unroll
        for (int t = 0; t < 16; t++) {
            segoff[t] = acc;
            acc += ((tot[t] + 15) >> 4) << 4;
        }
        segoff[16] = acc;
    }
    __syncthreads();
    #pragma unroll
    for (int i = 0; i < 16; i++) {
        int b = l + 64 * i;
        pos_base[b * 16 + w] = segoff[w] + lane_excl + pre[i];
    }
    // pad slots of this type's segment -> -1
    if (l == 0) {
        for (int p = segoff[w] + tot[w]; p < segoff[w + 1]; p++) sorted_idx[p] = -1;
    }
    // tile types for this segment
    for (int ti = (segoff[w] >> 4) + l; ti < (segoff[w + 1] >> 4); ti += 64)
        tile_type[ti] = w;
    __syncthreads();
    const int P16 = segoff[16] >> 4;
    for (int ti = P16 + tid; ti < NT_MAX; ti += 1024) tile_type[ti] = -1;
    // weight pre-conversion
    for (int i = tid; i < 16 * 32 * 16; i += 1024) W0bf[i] = f2bf(W0g[i]);
    for (int i = tid; i < 16 * 8 * 32; i += 1024) W1bf[i] = f2bf(W1g[i]);
}

// ---- 3. stable scatter into type-sorted padded index array ----
__global__ __launch_bounds__(TPB)
void nep_scatter(const int* __restrict__ ij, const int* __restrict__ pos_base,
                 int* __restrict__ sorted_idx)
{
    __shared__ unsigned char sty[TPB];
    __shared__ int sbase[16];
    const int tid = threadIdx.x, b = blockIdx.x;
    const int t = ij[b * TPB + tid];
    sty[tid] = (unsigned char)t;
    if (tid < 16) sbase[tid] = pos_base[b * 16 + tid];
    __syncthreads();
    const uchar4* s4 = (const uchar4*)sty;
    int rank = 0;
    #pragma unroll 8
    for (int j4 = 0; j4 < TPB / 4; j4++) {
        uchar4 v = s4[j4];
        int j = j4 * 4;
        rank += ((v.x == t) & (j + 0 < tid)) + ((v.y == t) & (j + 1 < tid))
              + ((v.z == t) & (j + 2 < tid)) + ((v.w == t) & (j + 3 < tid));
    }
    sorted_idx[sbase[t] + rank] = b * TPB + tid;
}

// ---- 4/6. MFMA mains ----
// Tile = 16 pairs of one type. MFMA1 (x2): C1[h, p] = W0[t] @ fn  (K=16 in slots hi<2).
// PHASE 0: BN1 stats from C1. PHASE 1: BN1 affine + SiLU in-register, repack C1
// (verified layout col=lane&15,row=(lane>>4)*4+reg) directly as B2, one MFMA ->
// out2[n, p]; write pre-BN2 out2; BN2 stats. Pad columns masked to 0.
template<int PHASE>
__global__ __launch_bounds__(TPB)
void nep_mfma(const int* __restrict__ tile_type, const int* __restrict__ sorted_idx,
              const float* __restrict__ fn, const short* __restrict__ W0bf,
              const short* __restrict__ W1bf, const float* __restrict__ ab1g,
              float* __restrict__ partial, float* __restrict__ out)
{
    __shared__ float rS[4][32];
    __shared__ float rQ[4][32];

    const int tid = threadIdx.x;
    const int wave = tid >> 6;
    const int wid = blockIdx.x * 4 + wave;     // 4096 waves
    const int l = tid & 63;
    const int p = l & 15;                      // pair column
    const int hi = l >> 4;

    float a1lo[4], b1lo[4], a1hi[4], b1hi[4];
    if constexpr (PHASE == 1) {
        #pragma unroll
        for (int r = 0; r < 4; r++) {
            int h = hi * 4 + r;
            a1lo[r] = ab1g[h];      b1lo[r] = ab1g[32 + h];
            a1hi[r] = ab1g[16 + h]; b1hi[r] = ab1g[48 + h];
        }
    }

    float s1[8], s2[8];
    #pragma unroll
    for (int c = 0; c < 8; c++) { s1[c] = 0.f; s2[c] = 0.f; }

    #pragma unroll 1
    for (int it = 0; it < 5; it++) {
        const int tile = wid + it * 4096;
        if (tile >= NT_MAX) break;
        const int t = tile_type[tile];
        if (t < 0) continue;
        const int idx = sorted_idx[tile * 16 + p];

        // fn B-frag: slots (hi<2, r) hold k = hi*8+r; others zero (K pad)
        short8 bF = {0, 0, 0, 0, 0, 0, 0, 0};
        if (hi < 2 && idx >= 0) {
            const float4* f4 = (const float4*)(fn + (size_t)idx * 16 + hi * 8);
            float4 u = f4[0], v = f4[1];
            bF[0] = f2bf(u.x); bF[1] = f2bf(u.y); bF[2] = f2bf(u.z); bF[3] = f2bf(u.w);
            bF[4] = f2bf(v.x); bF[5] = f2bf(v.y); bF[6] = f2bf(v.z); bF[7] = f2bf(v.w);
        }
        // W0 A-frags (rows h = hs*16 + p), same slot packing
        short8 a0 = {0, 0, 0, 0, 0, 0, 0, 0};
        short8 a1 = {0, 0, 0, 0, 0, 0, 0, 0};
        if (hi < 2) {
            a0 = *(const short8*)(W0bf + t * 512 + p * 16 + hi * 8);
            a1 = *(const short8*)(W0bf + t * 512 + 256 + p * 16 + hi * 8);
        }
        f32x4 c0 = {0.f, 0.f, 0.f, 0.f};
        f32x4 c1 = {0.f, 0.f, 0.f, 0.f};
        c0 = __builtin_amdgcn_mfma_f32_16x16x32_bf16(a0, bF, c0, 0, 0, 0);
        c1 = __builtin_amdgcn_mfma_f32_16x16x32_bf16(a1, bF, c1, 0, 0, 0);
        // c0[r] = out1[hi*4+r][p], c1[r] = out1[16+hi*4+r][p]

        if constexpr (PHASE == 0) {
            #pragma unroll
            for (int r = 0; r < 4; r++) {
                s1[r]     += c0[r]; s2[r]     += c0[r] * c0[r];
                s1[4 + r] += c1[r]; s2[4 + r] += c1[r] * c1[r];
            }
        } else {
            // BN1 affine + SiLU, mask pad columns, repack as B2 (k' = f2(hi,r))
            const bool valid = (idx >= 0);
            short8 bS;
            #pragma unroll
            for (int r = 0; r < 4; r++) {
                float x0 = a1lo[r] * c0[r] + b1lo[r];
                float x1 = a1hi[r] * c1[r] + b1hi[r];
                float v0 = valid ? silu_f(x0) : 0.f;
                float v1 = valid ? silu_f(x1) : 0.f;
                bS[r] = f2bf(v0);
                bS[4 + r] = f2bf(v1);
            }
            // W1 A2-frag: rows n = p (valid < 8), k' = f2(hi,r)
            short8 a2 = {0, 0, 0, 0, 0, 0, 0, 0};
            if (p < 8) {
                const short4* wa = (const short4*)(W1bf + t * 256 + p * 32 + hi * 4);
                const short4* wb = (const short4*)(W1bf + t * 256 + p * 32 + 16 + hi * 4);
                short4 A = wa[0], B = wb[0];
                a2[0] = A.x; a2[1] = A.y; a2[2] = A.z; a2[3] = A.w;
                a2[4] = B.x; a2[5] = B.y; a2[6] = B.z; a2[7] = B.w;
            }
            f32x4 c2 = {0.f, 0.f, 0.f, 0.f};
            c2 = __builtin_amdgcn_mfma_f32_16x16x32_bf16(a2, bS, c2, 0, 0, 0);
            // c2[r] = out2[n = hi*4+r][p] (rows >= 8 are zero)
            if (hi < 2 && idx >= 0) {
                float4 o;
                o.x = c2[0]; o.y = c2[1]; o.z = c2[2]; o.w = c2[3];
                *(float4*)(out + (size_t)idx * 8 + hi * 4) = o;
            }
            #pragma unroll
            for (int r = 0; r < 4; r++) { s1[r] += c2[r]; s2[r] += c2[r] * c2[r]; }
        }
    }

    // reduce over pair columns p (xor 1,2,4,8 stays within the hi-group)
    #pragma unroll
    for (int c = 0; c < 8; c++) {
        float v1 = s1[c], v2 = s2[c];
        v1 += __shfl_xor(v1, 1, 64);  v2 += __shfl_xor(v2, 1, 64);
        v1 += __shfl_xor(v1, 2, 64);  v2 += __shfl_xor(v2, 2, 64);
        v1 += __shfl_xor(v1, 4, 64);  v2 += __shfl_xor(v2, 4, 64);
        v1 += __shfl_xor(v1, 8, 64);  v2 += __shfl_xor(v2, 8, 64);
        s1[c] = v1; s2[c] = v2;
    }
    if constexpr (PHASE == 0) {
        if (p == 0) {
            #pragma unroll
            for (int r = 0; r < 4; r++) {
                rS[wave][hi * 4 + r] = s1[r];      rQ[wave][hi * 4 + r] = s2[r];
                rS[wave][16 + hi * 4 + r] = s1[4 + r]; rQ[wave][16 + hi * 4 + r] = s2[4 + r];
            }
        }
        __syncthreads();
        if (tid < 32) {
            float a = rS[0][tid] + rS[1][tid] + rS[2][tid] + rS[3][tid];
            float b = rQ[0][tid] + rQ[1][tid] + rQ[2][tid] + rQ[3][tid];
            partial[blockIdx.x * 64 + tid]      = a;
            partial[blockIdx.x * 64 + 32 + tid] = b;
        }
    } else {
        if (p == 0 && hi < 2) {
            #pragma unroll
            for (int r = 0; r < 4; r++) {
                rS[wave][hi * 4 + r] = s1[r];
                rQ[wave][hi * 4 + r] = s2[r];
            }
        }
        __syncthreads();
        if (tid < 8) {
            float a = rS[0][tid] + rS[1][tid] + rS[2][tid] + rS[3][tid];
            float b = rQ[0][tid] + rQ[1][tid] + rQ[2][tid] + rQ[3][tid];
            partial[blockIdx.x * 16 + tid]     = a;
            partial[blockIdx.x * 16 + 8 + tid] = b;
        }
    }
}

// ---- 5/7. fold stats into per-channel affine ----
template<int NS, int JW, int NB>
__global__ void nep_finalize(const float* __restrict__ partial,
                             const float* __restrict__ gamma,
                             const float* __restrict__ beta,
                             const int* __restrict__ norm,
                             float* __restrict__ ab)
{
    __shared__ float ssum[JW][NS];
    __shared__ float ssq[JW][NS];
    const int c = threadIdx.x & (NS - 1);
    const int j = threadIdx.x / NS;
    float s = 0.f, q = 0.f;
    for (int blk = j; blk < NB; blk += JW) {
        s += partial[blk * (2 * NS) + c];
        q += partial[blk * (2 * NS) + NS + c];
    }
    ssum[j][c] = s; ssq[j][c] = q;
    __syncthreads();
    if (threadIdx.x < NS) {
        float st = 0.f, qt = 0.f;
        #pragma unroll
        for (int jj = 0; jj < JW; jj++) { st += ssum[jj][c]; qt += ssq[jj][c]; }
        const float invE = 1.0f / (float)E_TOTAL;
        float mean = st * invE;
        float var  = qt * invE - mean * mean;
        float inv  = rsqrtf(var + 1e-5f);
        float a, b;
        if (*norm) { a = gamma[c] * inv; b = beta[c] - mean * a; }
        else       { a = 1.f; b = 0.f; }
        ab[c] = a;
        ab[NS + c] = b;
    }
}

// ---- 8. streaming BN2 epilogue: out = silu(a2*out + b2) ----
__global__ __launch_bounds__(TPB)
void nep_bn2(float* __restrict__ out, const float* __restrict__ ab2)
{
    __shared__ float sA[8], sB[8];
    if (threadIdx.x < 8) { sA[threadIdx.x] = ab2[threadIdx.x]; sB[threadIdx.x] = ab2[8 + threadIdx.x]; }
    __syncthreads();
    const int i = blockIdx.x * TPB + threadIdx.x;
    float4 v = ((const float4*)out)[i];
    const int c0 = (i & 1) * 4;
    float a0 = sA[c0], a1 = sA[c0 + 1], a2 = sA[c0 + 2], a3 = sA[c0 + 3];
    float b0 = sB[c0], b1 = sB[c0 + 1], b2 = sB[c0 + 2], b3 = sB[c0 + 3];
    v.x = silu_f(a0 * v.x + b0);
    v.y = silu_f(a1 * v.y + b1);
    v.z = silu_f(a2 * v.z + b2);
    v.w = silu_f(a3 * v.w + b3);
    ((float4*)out)[i] = v;
}

extern "C" void kernel_launch(void* const* d_in, const int* in_sizes, int n_in,
                              void* d_out, int out_size, void* d_ws, size_t ws_size,
                              hipStream_t stream)
{
    const int*   ij   = (const int*)d_in[0];
    const float* fn   = (const float*)d_in[1];
    const float* W0   = (const float*)d_in[2];
    const float* W1   = (const float*)d_in[3];
    const float* g1   = (const float*)d_in[4];
    const float* b1   = (const float*)d_in[5];
    const float* g2   = (const float*)d_in[6];
    const float* b2   = (const float*)d_in[7];
    const int*   norm = (const int*)d_in[8];
    float* out = (float*)d_out;

    int*   counts     = (int*)d_ws;                       // 1024*16
    int*   pos_base   = counts + NHBLK * 16;              // 1024*16
    int*   sorted_idx = pos_base + NHBLK * 16;            // NT_MAX*16
    int*   tile_type  = sorted_idx + NT_MAX * 16;         // NT_MAX
    short* W0bf       = (short*)(tile_type + NT_MAX);     // 8192 shorts
    short* W1bf       = W0bf + 8192;                      // 4096 shorts
    float* p1         = (float*)(W1bf + 4096);            // 1024*64
    float* p2         = p1 + NMBLK * 64;                  // 1024*16
    float* ab1        = p2 + NMBLK * 16;                  // 64
    float* ab2        = ab1 + 64;                         // 16

    nep_hist<<<NHBLK, TPB, 0, stream>>>(ij, counts);
    nep_scan<<<1, 1024, 0, stream>>>(counts, pos_base, tile_type, sorted_idx,
                                     W0, W1, W0bf, W1bf);
    nep_scatter<<<NHBLK, TPB, 0, stream>>>(ij, pos_base, sorted_idx);

    nep_mfma<0><<<NMBLK, TPB, 0, stream>>>(tile_type, sorted_idx, fn, W0bf, W1bf,
                                           nullptr, p1, nullptr);
    nep_finalize<32, 16, NMBLK><<<1, 512, 0, stream>>>(p1, g1, b1, norm, ab1);
    nep_mfma<1><<<NMBLK, TPB, 0, stream>>>(tile_type, sorted_idx, fn, W0bf, W1bf,
                                           ab1, p2, out);
    nep_finalize<8, 32, NMBLK><<<1, 256, 0, stream>>>(p2, g2, b2, norm, ab2);
    nep_bn2<<<(E_TOTAL * 8 / 4) / TPB, TPB, 0, stream>>>(out, ab2);
}

// Round 11
// 80.904 us; speedup vs baseline: 1.2323x; 1.2323x over previous
//
#include <hip/hip_runtime.h>

#define E_TOTAL 262144
#define TPB 256
#define NBLK 1024
#define CHUNK 256
#define MAXT 32              // max 16-pair tiles per chunk (hard bound 31)

typedef __attribute__((ext_vector_type(8))) short short8;
typedef __attribute__((ext_vector_type(4))) float f32x4;

__device__ __forceinline__ float silu_f(float x) { return x / (1.0f + __expf(-x)); }

// RNE float -> bf16 bits
__device__ __forceinline__ short f2bf(float f) {
    unsigned int u = __float_as_uint(f);
    u += 0x7fffu + ((u >> 16) & 1u);
    return (short)(u >> 16);
}

// Each block: sort its 256-pair chunk by type (stable rank-scan), build <=31
// 16-pair tiles, stage W0/W1/fn as bf16 in LDS, run MFMA per tile.
// PHASE 0: C1 = W0[t] @ fn (2 MFMAs/tile); BN1 sum/sumsq -> partial.
// PHASE 1: recompute C1, BN1 affine + SiLU in-register, repack as B2 (C-layout
//          == B-layout bijection, HW-verified R9), MFMA2 -> pre-BN2 out2;
//          write out2 to out; BN2 stats -> partial.
template<int PHASE>
__global__ __launch_bounds__(TPB, 4)
void nep_main(const int* __restrict__ ij, const float* __restrict__ fn,
              const float* __restrict__ W0, const float* __restrict__ W1,
              const float* __restrict__ ab1g,
              float* __restrict__ partial, float* __restrict__ out)
{
    __shared__ __align__(16) short sW0[16 * 512];                    // [t][h][k] bf16 16KB
    __shared__ __align__(16) short sW1[(PHASE == 1) ? 16 * 256 : 8]; // [t][n][h] bf16 8KB
    __shared__ __align__(16) short sfn[CHUNK * 16];                  // chunk fn bf16 8KB
    __shared__ unsigned char sty[CHUNK];
    __shared__ int soff[16];
    __shared__ int tstart[17];
    __shared__ short slotp[MAXT * 16];   // tile slot -> local pair (-1 pad)
    __shared__ char ttype[MAXT];
    __shared__ float rS[4][32], rQ[4][32];
    __shared__ float sAB1[64];

    const int tid  = threadIdx.x;
    const int bid  = blockIdx.x;
    const int l    = tid & 63;
    const int wave = tid >> 6;
    const int p    = l & 15;             // pair column within tile
    const int hi   = l >> 4;             // k-slot group / row group
    const int base = bid * CHUNK;

    // ---- stage weights (fp32 -> bf16) into LDS ----
    #pragma unroll
    for (int i = 0; i < 32; i++) sW0[tid + i * TPB] = f2bf(W0[tid + i * TPB]);
    if constexpr (PHASE == 1) {
        #pragma unroll
        for (int i = 0; i < 16; i++) sW1[tid + i * TPB] = f2bf(W1[tid + i * TPB]);
        if (tid < 64) sAB1[tid] = ab1g[tid];
    }
    // ---- stage chunk fn (fp32 -> bf16): one pair per thread ----
    {
        const float4* f4 = (const float4*)(fn + (size_t)(base + tid) * 16);
        float4 u0 = f4[0], u1 = f4[1], u2 = f4[2], u3 = f4[3];
        short8 w0, w1;
        w0[0]=f2bf(u0.x); w0[1]=f2bf(u0.y); w0[2]=f2bf(u0.z); w0[3]=f2bf(u0.w);
        w0[4]=f2bf(u1.x); w0[5]=f2bf(u1.y); w0[6]=f2bf(u1.z); w0[7]=f2bf(u1.w);
        w1[0]=f2bf(u2.x); w1[1]=f2bf(u2.y); w1[2]=f2bf(u2.z); w1[3]=f2bf(u2.w);
        w1[4]=f2bf(u3.x); w1[5]=f2bf(u3.y); w1[6]=f2bf(u3.z); w1[7]=f2bf(u3.w);
        *(short8*)(sfn + tid * 16)     = w0;
        *(short8*)(sfn + tid * 16 + 8) = w1;
    }
    if (tid < MAXT * 16 / 2) ((int*)slotp)[tid] = -1;

    // ---- local stable counting sort by type ----
    const int t0 = ij[base + tid];
    sty[tid] = (unsigned char)t0;
    __syncthreads();
    const uchar4* s4 = (const uchar4*)sty;
    int rank = 0;
    #pragma unroll 8
    for (int j4 = 0; j4 < CHUNK / 4; j4++) {
        uchar4 v = s4[j4];
        int j = j4 * 4;
        rank += ((v.x == t0) & (j + 0 < tid)) + ((v.y == t0) & (j + 1 < tid))
              + ((v.z == t0) & (j + 2 < tid)) + ((v.w == t0) & (j + 3 < tid));
    }
    if (tid < 16) {
        int c = 0;
        #pragma unroll 8
        for (int j4 = 0; j4 < CHUNK / 4; j4++) {
            uchar4 v = s4[j4];
            c += (v.x == tid) + (v.y == tid) + (v.z == tid) + (v.w == tid);
        }
        soff[tid] = c;
    }
    __syncthreads();
    if (tid == 0) {
        int acc = 0;
        #pragma unroll
        for (int t = 0; t < 16; t++) { tstart[t] = acc; acc += (soff[t] + 15) >> 4; }
        tstart[16] = acc;
    }
    __syncthreads();
    {
        int ti = tstart[t0] + (rank >> 4);
        slotp[ti * 16 + (rank & 15)] = (short)tid;
        ttype[ti] = (char)t0;                 // same-value races benign
    }
    __syncthreads();
    const int ntiles = tstart[16];            // <= 31

    float a1r[4], b1r[4], a1R[4], b1R[4];
    if constexpr (PHASE == 1) {
        #pragma unroll
        for (int r = 0; r < 4; r++) {
            a1r[r] = sAB1[hi * 4 + r];      b1r[r] = sAB1[32 + hi * 4 + r];
            a1R[r] = sAB1[16 + hi * 4 + r]; b1R[r] = sAB1[48 + hi * 4 + r];
        }
    }

    float s1[8], s2[8];
    #pragma unroll
    for (int c = 0; c < 8; c++) { s1[c] = 0.f; s2[c] = 0.f; }

    // ---- tile loop: this wave handles tiles wave, wave+4, ... ----
    #pragma unroll 1
    for (int it = 0; it < 8; it++) {
        const int ti = wave + it * 4;
        if (ti >= ntiles) break;
        const int t  = (int)ttype[ti];
        const int sp = (int)slotp[ti * 16 + p];

        // B1-frag: fn for pair column p, k-slots (hi<2, r) = k=hi*8+r
        short8 bF = {0,0,0,0,0,0,0,0};
        if (hi < 2 && sp >= 0)
            bF = *(const short8*)(sfn + sp * 16 + hi * 8);
        // A-frags: W0 rows h = hs*16 + p, same slot packing
        short8 a0 = {0,0,0,0,0,0,0,0};
        short8 a1 = {0,0,0,0,0,0,0,0};
        if (hi < 2) {
            a0 = *(const short8*)(sW0 + t * 512 + p * 16 + hi * 8);
            a1 = *(const short8*)(sW0 + t * 512 + 256 + p * 16 + hi * 8);
        }
        f32x4 z = {0.f, 0.f, 0.f, 0.f};
        f32x4 c0 = __builtin_amdgcn_mfma_f32_16x16x32_bf16(a0, bF, z, 0, 0, 0);
        f32x4 c1 = __builtin_amdgcn_mfma_f32_16x16x32_bf16(a1, bF, z, 0, 0, 0);
        // c0[r] = out1[hi*4+r][p], c1[r] = out1[16+hi*4+r][p]

        if constexpr (PHASE == 0) {
            #pragma unroll
            for (int r = 0; r < 4; r++) {
                s1[r]     += c0[r]; s2[r]     += c0[r] * c0[r];
                s1[4 + r] += c1[r]; s2[4 + r] += c1[r] * c1[r];
            }
        } else {
            const bool vs = (sp >= 0);
            short8 bS;
            #pragma unroll
            for (int r = 0; r < 4; r++) {
                float x0 = a1r[r] * c0[r] + b1r[r];
                float x1 = a1R[r] * c1[r] + b1R[r];
                bS[r]     = f2bf(vs ? silu_f(x0) : 0.f);
                bS[4 + r] = f2bf(vs ? silu_f(x1) : 0.f);
            }
            // A2-frag: W1 rows n = p (<8), k' slots = same bijection
            short8 a2v = {0,0,0,0,0,0,0,0};
            if (p < 8) {
                short4 A = *(const short4*)(sW1 + t * 256 + p * 32 + hi * 4);
                short4 B = *(const short4*)(sW1 + t * 256 + p * 32 + 16 + hi * 4);
                a2v[0] = A.x; a2v[1] = A.y; a2v[2] = A.z; a2v[3] = A.w;
                a2v[4] = B.x; a2v[5] = B.y; a2v[6] = B.z; a2v[7] = B.w;
            }
            f32x4 c2 = __builtin_amdgcn_mfma_f32_16x16x32_bf16(a2v, bS, z, 0, 0, 0);
            // c2[r] = out2[n = hi*4+r][p] (rows >= 8 zero)
            if (hi < 2 && sp >= 0) {
                float4 o;
                o.x = c2[0]; o.y = c2[1]; o.z = c2[2]; o.w = c2[3];
                *(float4*)(out + (size_t)(base + sp) * 8 + hi * 4) = o;
            }
            #pragma unroll
            for (int r = 0; r < 4; r++) { s1[r] += c2[r]; s2[r] += c2[r] * c2[r]; }
        }
    }

    // ---- reduce over pair columns p (xor 1,2,4,8 stays within hi-group) ----
    constexpr int NC = (PHASE == 0) ? 8 : 4;
    #pragma unroll
    for (int c = 0; c < NC; c++) {
        float v1 = s1[c], v2 = s2[c];
        v1 += __shfl_xor(v1, 1, 64); v2 += __shfl_xor(v2, 1, 64);
        v1 += __shfl_xor(v1, 2, 64); v2 += __shfl_xor(v2, 2, 64);
        v1 += __shfl_xor(v1, 4, 64); v2 += __shfl_xor(v2, 4, 64);
        v1 += __shfl_xor(v1, 8, 64); v2 += __shfl_xor(v2, 8, 64);
        s1[c] = v1; s2[c] = v2;
    }
    if constexpr (PHASE == 0) {
        if (p == 0) {
            #pragma unroll
            for (int r = 0; r < 4; r++) {
                rS[wave][hi * 4 + r]      = s1[r];     rQ[wave][hi * 4 + r]      = s2[r];
                rS[wave][16 + hi * 4 + r] = s1[4 + r]; rQ[wave][16 + hi * 4 + r] = s2[4 + r];
            }
        }
        __syncthreads();
        if (tid < 32) {
            float a = rS[0][tid] + rS[1][tid] + rS[2][tid] + rS[3][tid];
            float b = rQ[0][tid] + rQ[1][tid] + rQ[2][tid] + rQ[3][tid];
            partial[bid * 64 + tid]      = a;
            partial[bid * 64 + 32 + tid] = b;
        }
    } else {
        if (p == 0 && hi < 2) {
            #pragma unroll
            for (int r = 0; r < 4; r++) {
                rS[wave][hi * 4 + r] = s1[r];
                rQ[wave][hi * 4 + r] = s2[r];
            }
        }
        __syncthreads();
        if (tid < 8) {
            float a = rS[0][tid] + rS[1][tid] + rS[2][tid] + rS[3][tid];
            float b = rQ[0][tid] + rQ[1][tid] + rQ[2][tid] + rQ[3][tid];
            partial[bid * 16 + tid]     = a;
            partial[bid * 16 + 8 + tid] = b;
        }
    }
}

// ---- fold stats into per-channel affine ----
template<int NS, int JW>
__global__ void nep_finalize(const float* __restrict__ partial,
                             const float* __restrict__ gamma,
                             const float* __restrict__ beta,
                             const int* __restrict__ norm,
                             float* __restrict__ ab)
{
    __shared__ float ssum[JW][NS];
    __shared__ float ssq[JW][NS];
    const int c = threadIdx.x & (NS - 1);
    const int j = threadIdx.x / NS;
    float s = 0.f, q = 0.f;
    for (int blk = j; blk < NBLK; blk += JW) {
        s += partial[blk * (2 * NS) + c];
        q += partial[blk * (2 * NS) + NS + c];
    }
    ssum[j][c] = s; ssq[j][c] = q;
    __syncthreads();
    if (threadIdx.x < NS) {
        float st = 0.f, qt = 0.f;
        #pragma unroll
        for (int jj = 0; jj < JW; jj++) { st += ssum[jj][c]; qt += ssq[jj][c]; }
        const float invE = 1.0f / (float)E_TOTAL;
        float mean = st * invE;
        float var  = qt * invE - mean * mean;
        float inv  = rsqrtf(var + 1e-5f);
        float a, b;
        if (*norm) { a = gamma[c] * inv; b = beta[c] - mean * a; }
        else       { a = 1.f; b = 0.f; }
        ab[c] = a;
        ab[NS + c] = b;
    }
}

// ---- streaming BN2 epilogue: out = silu(a2*out + b2) ----
__global__ __launch_bounds__(TPB)
void nep_bn2(float* __restrict__ out, const float* __restrict__ ab2)
{
    __shared__ float sA[8], sB[8];
    if (threadIdx.x < 8) { sA[threadIdx.x] = ab2[threadIdx.x]; sB[threadIdx.x] = ab2[8 + threadIdx.x]; }
    __syncthreads();
    const int i = blockIdx.x * TPB + threadIdx.x;
    float4 v = ((const float4*)out)[i];
    const int c0 = (i & 1) * 4;
    float a0 = sA[c0], a1 = sA[c0 + 1], a2 = sA[c0 + 2], a3 = sA[c0 + 3];
    float b0 = sB[c0], b1 = sB[c0 + 1], b2 = sB[c0 + 2], b3 = sB[c0 + 3];
    v.x = silu_f(a0 * v.x + b0);
    v.y = silu_f(a1 * v.y + b1);
    v.z = silu_f(a2 * v.z + b2);
    v.w = silu_f(a3 * v.w + b3);
    ((float4*)out)[i] = v;
}

extern "C" void kernel_launch(void* const* d_in, const int* in_sizes, int n_in,
                              void* d_out, int out_size, void* d_ws, size_t ws_size,
                              hipStream_t stream)
{
    const int*   ij   = (const int*)d_in[0];
    const float* fn   = (const float*)d_in[1];
    const float* W0   = (const float*)d_in[2];
    const float* W1   = (const float*)d_in[3];
    const float* g1   = (const float*)d_in[4];
    const float* b1   = (const float*)d_in[5];
    const float* g2   = (const float*)d_in[6];
    const float* b2   = (const float*)d_in[7];
    const int*   norm = (const int*)d_in[8];
    float* out = (float*)d_out;

    float* p1  = (float*)d_ws;        // 1024*64
    float* p2  = p1 + NBLK * 64;      // 1024*16
    float* ab1 = p2 + NBLK * 16;      // 64
    float* ab2 = ab1 + 64;            // 16

    nep_main<0><<<NBLK, TPB, 0, stream>>>(ij, fn, W0, W1, nullptr, p1, nullptr);
    nep_finalize<32, 16><<<1, 512, 0, stream>>>(p1, g1, b1, norm, ab1);
    nep_main<1><<<NBLK, TPB, 0, stream>>>(ij, fn, W0, W1, ab1, p2, out);
    nep_finalize<8, 32><<<1, 256, 0, stream>>>(p2, g2, b2, norm, ab2);
    nep_bn2<<<(E_TOTAL * 8 / 4) / TPB, TPB, 0, stream>>>(out, ab2);
}

// Round 12
// 49.757 us; speedup vs baseline: 2.0037x; 1.6260x over previous
//
#include <hip/hip_runtime.h>

#define E_TOTAL 262144
#define TPB 256
#define NBLK 1024
#define CHUNK 256
#define MAXT 32              // max 16-pair tiles per chunk (hard bound 31)

typedef __attribute__((ext_vector_type(8))) short short8;
typedef __attribute__((ext_vector_type(4))) float f32x4;

__device__ __forceinline__ float silu_f(float x) { return x / (1.0f + __expf(-x)); }

// RNE float -> bf16 bits
__device__ __forceinline__ short f2bf(float f) {
    unsigned int u = __float_as_uint(f);
    u += 0x7fffu + ((u >> 16) & 1u);
    return (short)(u >> 16);
}

// Each block: ballot-sort its 256-pair chunk by type, build <=31 16-pair tiles,
// stage W0/W1/fn as bf16 in LDS, run MFMA per tile.
// PHASE 0: C1 = W0[t] @ fn (2 MFMAs/tile); BN1 sum/sumsq -> partial.
// PHASE 1: recompute C1, BN1 affine + SiLU in-register, repack as B2 (C-layout
//          == B-layout bijection, HW-verified R9/R11), MFMA2 -> pre-BN2 out2;
//          write to out; BN2 stats -> partial.
template<int PHASE>
__global__ __launch_bounds__(TPB, 4)
void nep_main(const int* __restrict__ ij, const float* __restrict__ fn,
              const float* __restrict__ W0, const float* __restrict__ W1,
              const float* __restrict__ ab1g,
              float* __restrict__ partial, float* __restrict__ out)
{
    __shared__ __align__(16) short sW0[16 * 512];                    // [t][h][k] bf16 16KB
    __shared__ __align__(16) short sW1[(PHASE == 1) ? 16 * 256 : 8]; // [t][n][h] bf16 8KB
    __shared__ __align__(16) short sfn[CHUNK * 16];                  // chunk fn bf16 8KB
    __shared__ int whist[4][16];
    __shared__ int woff[4][16];
    __shared__ int soff[16];
    __shared__ int tstart[17];
    __shared__ short slotp[MAXT * 16];   // tile slot -> local pair (-1 pad)
    __shared__ char ttype[MAXT];
    __shared__ float rS[4][32], rQ[4][32];
    __shared__ float sAB1[64];

    const int tid  = threadIdx.x;
    const int bid  = blockIdx.x;
    const int l    = tid & 63;
    const int wave = tid >> 6;
    const int p    = l & 15;             // pair column within tile
    const int hi   = l >> 4;             // k-slot / row group
    const int base = bid * CHUNK;

    // ---- issue independent global loads early ----
    const int t0 = ij[base + tid];
    const float4* f4g = (const float4*)(fn + (size_t)(base + tid) * 16);
    float4 u0 = f4g[0], u1 = f4g[1], u2 = f4g[2], u3 = f4g[3];

    // ---- ballot multi-split sort (stable: wave-major, lane-major) ----
    unsigned long long bl0 = __ballot(t0 & 1);
    unsigned long long bl1 = __ballot(t0 & 2);
    unsigned long long bl2 = __ballot(t0 & 4);
    unsigned long long bl3 = __ballot(t0 & 8);
    unsigned long long mself = ((t0 & 1) ? bl0 : ~bl0) & ((t0 & 2) ? bl1 : ~bl1)
                             & ((t0 & 4) ? bl2 : ~bl2) & ((t0 & 8) ? bl3 : ~bl3);
    const int rank_w = __popcll(mself & ((1ull << l) - 1ull));
    if (l < 16) {
        const int t = l;
        unsigned long long mt = ((t & 1) ? bl0 : ~bl0) & ((t & 2) ? bl1 : ~bl1)
                              & ((t & 4) ? bl2 : ~bl2) & ((t & 8) ? bl3 : ~bl3);
        whist[wave][t] = __popcll(mt);
    }
    if (tid < MAXT * 16 / 2) ((int*)slotp)[tid] = -1;

    // ---- stage W0 (fp32 -> bf16, vectorized) ----
    {
        const float4* W04 = (const float4*)W0;
        #pragma unroll
        for (int i = 0; i < 8; i++) {
            float4 v = W04[tid + i * TPB];
            short4 s;
            s.x = f2bf(v.x); s.y = f2bf(v.y); s.z = f2bf(v.z); s.w = f2bf(v.w);
            *(short4*)(sW0 + (tid + i * TPB) * 4) = s;
        }
    }
    if constexpr (PHASE == 1) {
        const float4* W14 = (const float4*)W1;
        #pragma unroll
        for (int i = 0; i < 4; i++) {
            float4 v = W14[tid + i * TPB];
            short4 s;
            s.x = f2bf(v.x); s.y = f2bf(v.y); s.z = f2bf(v.z); s.w = f2bf(v.w);
            *(short4*)(sW1 + (tid + i * TPB) * 4) = s;
        }
        if (tid < 64) sAB1[tid] = ab1g[tid];
    }
    // ---- stage fn (fp32 -> bf16): one pair per thread ----
    {
        short8 w0, w1;
        w0[0]=f2bf(u0.x); w0[1]=f2bf(u0.y); w0[2]=f2bf(u0.z); w0[3]=f2bf(u0.w);
        w0[4]=f2bf(u1.x); w0[5]=f2bf(u1.y); w0[6]=f2bf(u1.z); w0[7]=f2bf(u1.w);
        w1[0]=f2bf(u2.x); w1[1]=f2bf(u2.y); w1[2]=f2bf(u2.z); w1[3]=f2bf(u2.w);
        w1[4]=f2bf(u3.x); w1[5]=f2bf(u3.y); w1[6]=f2bf(u3.z); w1[7]=f2bf(u3.w);
        *(short8*)(sfn + tid * 16)     = w0;
        *(short8*)(sfn + tid * 16 + 8) = w1;
    }
    __syncthreads();

    // ---- block-level type offsets ----
    if (tid < 16) {
        int c0 = whist[0][tid], c1 = whist[1][tid], c2 = whist[2][tid], c3 = whist[3][tid];
        woff[0][tid] = 0; woff[1][tid] = c0; woff[2][tid] = c0 + c1; woff[3][tid] = c0 + c1 + c2;
        soff[tid] = c0 + c1 + c2 + c3;
    }
    __syncthreads();
    if (tid == 0) {
        int acc = 0;
        #pragma unroll
        for (int t = 0; t < 16; t++) { tstart[t] = acc; acc += (soff[t] + 15) >> 4; }
        tstart[16] = acc;
    }
    __syncthreads();
    {
        const int rank = woff[wave][t0] + rank_w;
        const int ti = tstart[t0] + (rank >> 4);
        slotp[ti * 16 + (rank & 15)] = (short)tid;
        ttype[ti] = (char)t0;                 // same-value races benign
    }
    __syncthreads();
    const int ntiles = tstart[16];            // <= 31

    float a1r[4], b1r[4], a1R[4], b1R[4];
    if constexpr (PHASE == 1) {
        #pragma unroll
        for (int r = 0; r < 4; r++) {
            a1r[r] = sAB1[hi * 4 + r];      b1r[r] = sAB1[32 + hi * 4 + r];
            a1R[r] = sAB1[16 + hi * 4 + r]; b1R[r] = sAB1[48 + hi * 4 + r];
        }
    }

    float s1[8], s2[8];
    #pragma unroll
    for (int c = 0; c < 8; c++) { s1[c] = 0.f; s2[c] = 0.f; }

    // ---- tile loop: wave handles tiles wave, wave+4, ... ----
    #pragma unroll 1
    for (int it = 0; it < 8; it++) {
        const int ti = wave + it * 4;
        if (ti >= ntiles) break;
        const int t  = (int)ttype[ti];
        const int sp = (int)slotp[ti * 16 + p];

        short8 bF = {0,0,0,0,0,0,0,0};
        if (hi < 2 && sp >= 0)
            bF = *(const short8*)(sfn + sp * 16 + hi * 8);
        short8 a0 = {0,0,0,0,0,0,0,0};
        short8 a1 = {0,0,0,0,0,0,0,0};
        if (hi < 2) {
            a0 = *(const short8*)(sW0 + t * 512 + p * 16 + hi * 8);
            a1 = *(const short8*)(sW0 + t * 512 + 256 + p * 16 + hi * 8);
        }
        f32x4 z = {0.f, 0.f, 0.f, 0.f};
        f32x4 c0 = __builtin_amdgcn_mfma_f32_16x16x32_bf16(a0, bF, z, 0, 0, 0);
        f32x4 c1 = __builtin_amdgcn_mfma_f32_16x16x32_bf16(a1, bF, z, 0, 0, 0);
        // c0[r] = out1[hi*4+r][p], c1[r] = out1[16+hi*4+r][p]

        if constexpr (PHASE == 0) {
            #pragma unroll
            for (int r = 0; r < 4; r++) {
                s1[r]     += c0[r]; s2[r]     += c0[r] * c0[r];
                s1[4 + r] += c1[r]; s2[4 + r] += c1[r] * c1[r];
            }
        } else {
            const bool vs = (sp >= 0);
            short8 bS;
            #pragma unroll
            for (int r = 0; r < 4; r++) {
                float x0 = a1r[r] * c0[r] + b1r[r];
                float x1 = a1R[r] * c1[r] + b1R[r];
                bS[r]     = f2bf(vs ? silu_f(x0) : 0.f);
                bS[4 + r] = f2bf(vs ? silu_f(x1) : 0.f);
            }
            short8 a2v = {0,0,0,0,0,0,0,0};
            if (p < 8) {
                short4 A = *(const short4*)(sW1 + t * 256 + p * 32 + hi * 4);
                short4 B = *(const short4*)(sW1 + t * 256 + p * 32 + 16 + hi * 4);
                a2v[0] = A.x; a2v[1] = A.y; a2v[2] = A.z; a2v[3] = A.w;
                a2v[4] = B.x; a2v[5] = B.y; a2v[6] = B.z; a2v[7] = B.w;
            }
            f32x4 c2 = __builtin_amdgcn_mfma_f32_16x16x32_bf16(a2v, bS, z, 0, 0, 0);
            if (hi < 2 && sp >= 0) {
                float4 o;
                o.x = c2[0]; o.y = c2[1]; o.z = c2[2]; o.w = c2[3];
                *(float4*)(out + (size_t)(base + sp) * 8 + hi * 4) = o;
            }
            #pragma unroll
            for (int r = 0; r < 4; r++) { s1[r] += c2[r]; s2[r] += c2[r] * c2[r]; }
        }
    }

    // ---- reduce over pair columns p ----
    constexpr int NC = (PHASE == 0) ? 8 : 4;
    #pragma unroll
    for (int c = 0; c < NC; c++) {
        float v1 = s1[c], v2 = s2[c];
        v1 += __shfl_xor(v1, 1, 64); v2 += __shfl_xor(v2, 1, 64);
        v1 += __shfl_xor(v1, 2, 64); v2 += __shfl_xor(v2, 2, 64);
        v1 += __shfl_xor(v1, 4, 64); v2 += __shfl_xor(v2, 4, 64);
        v1 += __shfl_xor(v1, 8, 64); v2 += __shfl_xor(v2, 8, 64);
        s1[c] = v1; s2[c] = v2;
    }
    if constexpr (PHASE == 0) {
        if (p == 0) {
            #pragma unroll
            for (int r = 0; r < 4; r++) {
                rS[wave][hi * 4 + r]      = s1[r];     rQ[wave][hi * 4 + r]      = s2[r];
                rS[wave][16 + hi * 4 + r] = s1[4 + r]; rQ[wave][16 + hi * 4 + r] = s2[4 + r];
            }
        }
        __syncthreads();
        if (tid < 32) {
            float a = rS[0][tid] + rS[1][tid] + rS[2][tid] + rS[3][tid];
            float b = rQ[0][tid] + rQ[1][tid] + rQ[2][tid] + rQ[3][tid];
            partial[bid * 64 + tid]      = a;
            partial[bid * 64 + 32 + tid] = b;
        }
    } else {
        if (p == 0 && hi < 2) {
            #pragma unroll
            for (int r = 0; r < 4; r++) {
                rS[wave][hi * 4 + r] = s1[r];
                rQ[wave][hi * 4 + r] = s2[r];
            }
        }
        __syncthreads();
        if (tid < 8) {
            float a = rS[0][tid] + rS[1][tid] + rS[2][tid] + rS[3][tid];
            float b = rQ[0][tid] + rQ[1][tid] + rQ[2][tid] + rQ[3][tid];
            partial[bid * 16 + tid]     = a;
            partial[bid * 16 + 8 + tid] = b;
        }
    }
}

// ---- fold stats into per-channel affine ----
template<int NS, int JW>
__global__ __launch_bounds__(1024)
void nep_finalize(const float* __restrict__ partial,
                  const float* __restrict__ gamma,
                  const float* __restrict__ beta,
                  const int* __restrict__ norm,
                  float* __restrict__ ab)
{
    __shared__ float ssum[JW][NS];
    __shared__ float ssq[JW][NS];
    const int c = threadIdx.x & (NS - 1);
    const int j = threadIdx.x / NS;
    float s = 0.f, q = 0.f;
    for (int blk = j; blk < NBLK; blk += JW) {
        s += partial[blk * (2 * NS) + c];
        q += partial[blk * (2 * NS) + NS + c];
    }
    ssum[j][c] = s; ssq[j][c] = q;
    __syncthreads();
    if (threadIdx.x < NS) {
        float st = 0.f, qt = 0.f;
        #pragma unroll
        for (int jj = 0; jj < JW; jj++) { st += ssum[jj][c]; qt += ssq[jj][c]; }
        const float invE = 1.0f / (float)E_TOTAL;
        float mean = st * invE;
        float var  = qt * invE - mean * mean;
        float inv  = rsqrtf(var + 1e-5f);
        float a, b;
        if (*norm) { a = gamma[c] * inv; b = beta[c] - mean * a; }
        else       { a = 1.f; b = 0.f; }
        ab[c] = a;
        ab[NS + c] = b;
    }
}

// ---- streaming BN2 epilogue: out = silu(a2*out + b2) ----
__global__ __launch_bounds__(TPB)
void nep_bn2(float* __restrict__ out, const float* __restrict__ ab2)
{
    __shared__ float sA[8], sB[8];
    if (threadIdx.x < 8) { sA[threadIdx.x] = ab2[threadIdx.x]; sB[threadIdx.x] = ab2[8 + threadIdx.x]; }
    __syncthreads();
    const int i = blockIdx.x * TPB + threadIdx.x;
    float4 v = ((const float4*)out)[i];
    const int c0 = (i & 1) * 4;
    float a0 = sA[c0], a1 = sA[c0 + 1], a2 = sA[c0 + 2], a3 = sA[c0 + 3];
    float b0 = sB[c0], b1 = sB[c0 + 1], b2 = sB[c0 + 2], b3 = sB[c0 + 3];
    v.x = silu_f(a0 * v.x + b0);
    v.y = silu_f(a1 * v.y + b1);
    v.z = silu_f(a2 * v.z + b2);
    v.w = silu_f(a3 * v.w + b3);
    ((float4*)out)[i] = v;
}

extern "C" void kernel_launch(void* const* d_in, const int* in_sizes, int n_in,
                              void* d_out, int out_size, void* d_ws, size_t ws_size,
                              hipStream_t stream)
{
    const int*   ij   = (const int*)d_in[0];
    const float* fn   = (const float*)d_in[1];
    const float* W0   = (const float*)d_in[2];
    const float* W1   = (const float*)d_in[3];
    const float* g1   = (const float*)d_in[4];
    const float* b1   = (const float*)d_in[5];
    const float* g2   = (const float*)d_in[6];
    const float* b2   = (const float*)d_in[7];
    const int*   norm = (const int*)d_in[8];
    float* out = (float*)d_out;

    float* p1  = (float*)d_ws;        // 1024*64
    float* p2  = p1 + NBLK * 64;      // 1024*16
    float* ab1 = p2 + NBLK * 16;      // 64
    float* ab2 = ab1 + 64;            // 16

    nep_main<0><<<NBLK, TPB, 0, stream>>>(ij, fn, W0, W1, nullptr, p1, nullptr);
    nep_finalize<32, 32><<<1, 1024, 0, stream>>>(p1, g1, b1, norm, ab1);
    nep_main<1><<<NBLK, TPB, 0, stream>>>(ij, fn, W0, W1, ab1, p2, out);
    nep_finalize<8, 64><<<1, 512, 0, stream>>>(p2, g2, b2, norm, ab2);
    nep_bn2<<<(E_TOTAL * 8 / 4) / TPB, TPB, 0, stream>>>(out, ab2);
}

// Round 13
// 48.083 us; speedup vs baseline: 2.0735x; 1.0348x over previous
//
#include <hip/hip_runtime.h>

#define E_TOTAL 262144
#define TPB 512
#define NBLK 512
#define CHUNK 512
#define MAXT 48              // max 16-pair tiles per chunk (hard bound 47)

typedef __attribute__((ext_vector_type(8))) short short8;
typedef __attribute__((ext_vector_type(4))) float f32x4;

__device__ __forceinline__ float silu_f(float x) { return x / (1.0f + __expf(-x)); }

// RNE float -> bf16 bits
__device__ __forceinline__ short f2bf(float f) {
    unsigned int u = __float_as_uint(f);
    u += 0x7fffu + ((u >> 16) & 1u);
    return (short)(u >> 16);
}
__device__ __forceinline__ float bf2f(short s) {
    return __uint_as_float(((unsigned int)(unsigned short)s) << 16);
}

// Each block: ballot-sort its 512-pair chunk by type, build <=47 16-pair tiles,
// stage W0/W1/fn as bf16 in LDS, run MFMA per tile (bijective k-slot packing,
// HW-verified R9/R11/R12).
// PHASE 0: C1 = W0[t] @ fn (2 MFMAs/tile); BN1 sum/sumsq -> partial.
// PHASE 1: recompute C1, BN1 affine + SiLU in-register, repack as B2, MFMA2;
//          write pre-BN2 o2 as bf16 to o2b; BN2 stats -> partial.
template<int PHASE>
__global__ __launch_bounds__(TPB, 4)
void nep_main(const int* __restrict__ ij, const float* __restrict__ fn,
              const float* __restrict__ W0, const float* __restrict__ W1,
              const float* __restrict__ ab1g,
              float* __restrict__ partial, short* __restrict__ o2b)
{
    __shared__ __align__(16) short sW0[16 * 512];                    // 16KB
    __shared__ __align__(16) short sW1[(PHASE == 1) ? 16 * 256 : 8]; // 8KB
    __shared__ __align__(16) short sfn[CHUNK * 16];                  // 16KB
    __shared__ int whist[8][16];
    __shared__ int woff[8][16];
    __shared__ int soff[16];
    __shared__ int tstart[17];
    __shared__ short slotp[MAXT * 16];   // tile slot -> local pair (-1 pad)
    __shared__ char ttype[MAXT];
    __shared__ float rS[8][32], rQ[8][32];
    __shared__ float sAB1[64];

    const int tid  = threadIdx.x;
    const int bid  = blockIdx.x;
    const int l    = tid & 63;
    const int wave = tid >> 6;           // 0..7
    const int p    = l & 15;             // pair column within tile
    const int hi   = l >> 4;             // k-slot / row group
    const int base = bid * CHUNK;

    // ---- issue independent global loads early ----
    const int t0 = ij[base + tid];
    const float4* f4g = (const float4*)(fn + (size_t)(base + tid) * 16);
    float4 u0 = f4g[0], u1 = f4g[1], u2 = f4g[2], u3 = f4g[3];

    // ---- ballot multi-split sort (stable: wave-major, lane-major) ----
    unsigned long long bl0 = __ballot(t0 & 1);
    unsigned long long bl1 = __ballot(t0 & 2);
    unsigned long long bl2 = __ballot(t0 & 4);
    unsigned long long bl3 = __ballot(t0 & 8);
    unsigned long long mself = ((t0 & 1) ? bl0 : ~bl0) & ((t0 & 2) ? bl1 : ~bl1)
                             & ((t0 & 4) ? bl2 : ~bl2) & ((t0 & 8) ? bl3 : ~bl3);
    const int rank_w = __popcll(mself & ((1ull << l) - 1ull));
    if (l < 16) {
        const int t = l;
        unsigned long long mt = ((t & 1) ? bl0 : ~bl0) & ((t & 2) ? bl1 : ~bl1)
                              & ((t & 4) ? bl2 : ~bl2) & ((t & 8) ? bl3 : ~bl3);
        whist[wave][t] = __popcll(mt);
    }
    if (tid < MAXT * 16 / 2) ((int*)slotp)[tid] = -1;

    // ---- stage W0 (fp32 -> bf16, vectorized) ----
    {
        const float4* W04 = (const float4*)W0;
        #pragma unroll
        for (int i = 0; i < 4; i++) {
            float4 v = W04[tid + i * TPB];
            short4 s;
            s.x = f2bf(v.x); s.y = f2bf(v.y); s.z = f2bf(v.z); s.w = f2bf(v.w);
            *(short4*)(sW0 + (tid + i * TPB) * 4) = s;
        }
    }
    if constexpr (PHASE == 1) {
        const float4* W14 = (const float4*)W1;
        #pragma unroll
        for (int i = 0; i < 2; i++) {
            float4 v = W14[tid + i * TPB];
            short4 s;
            s.x = f2bf(v.x); s.y = f2bf(v.y); s.z = f2bf(v.z); s.w = f2bf(v.w);
            *(short4*)(sW1 + (tid + i * TPB) * 4) = s;
        }
        if (tid < 64) sAB1[tid] = ab1g[tid];
    }
    // ---- stage fn (fp32 -> bf16): one pair per thread ----
    {
        short8 w0, w1;
        w0[0]=f2bf(u0.x); w0[1]=f2bf(u0.y); w0[2]=f2bf(u0.z); w0[3]=f2bf(u0.w);
        w0[4]=f2bf(u1.x); w0[5]=f2bf(u1.y); w0[6]=f2bf(u1.z); w0[7]=f2bf(u1.w);
        w1[0]=f2bf(u2.x); w1[1]=f2bf(u2.y); w1[2]=f2bf(u2.z); w1[3]=f2bf(u2.w);
        w1[4]=f2bf(u3.x); w1[5]=f2bf(u3.y); w1[6]=f2bf(u3.z); w1[7]=f2bf(u3.w);
        *(short8*)(sfn + tid * 16)     = w0;
        *(short8*)(sfn + tid * 16 + 8) = w1;
    }
    __syncthreads();

    // ---- block-level type offsets (8-wave prefix) ----
    if (tid < 16) {
        int acc = 0;
        #pragma unroll
        for (int w = 0; w < 8; w++) { woff[w][tid] = acc; acc += whist[w][tid]; }
        soff[tid] = acc;
    }
    __syncthreads();
    if (tid == 0) {
        int acc = 0;
        #pragma unroll
        for (int t = 0; t < 16; t++) { tstart[t] = acc; acc += (soff[t] + 15) >> 4; }
        tstart[16] = acc;
    }
    __syncthreads();
    {
        const int rank = woff[wave][t0] + rank_w;
        const int ti = tstart[t0] + (rank >> 4);
        slotp[ti * 16 + (rank & 15)] = (short)tid;
        ttype[ti] = (char)t0;                 // same-value races benign
    }
    __syncthreads();
    const int ntiles = tstart[16];            // <= 47

    float a1r[4], b1r[4], a1R[4], b1R[4];
    if constexpr (PHASE == 1) {
        #pragma unroll
        for (int r = 0; r < 4; r++) {
            a1r[r] = sAB1[hi * 4 + r];      b1r[r] = sAB1[32 + hi * 4 + r];
            a1R[r] = sAB1[16 + hi * 4 + r]; b1R[r] = sAB1[48 + hi * 4 + r];
        }
    }

    float s1[8], s2[8];
    #pragma unroll
    for (int c = 0; c < 8; c++) { s1[c] = 0.f; s2[c] = 0.f; }

    // ---- tile loop: wave handles tiles wave, wave+8, ... ----
    #pragma unroll 1
    for (int it = 0; it < 6; it++) {
        const int ti = wave + it * 8;
        if (ti >= ntiles) break;
        const int t  = (int)ttype[ti];
        const int sp = (int)slotp[ti * 16 + p];

        short8 bF = {0,0,0,0,0,0,0,0};
        if (hi < 2 && sp >= 0)
            bF = *(const short8*)(sfn + sp * 16 + hi * 8);
        short8 a0 = {0,0,0,0,0,0,0,0};
        short8 a1 = {0,0,0,0,0,0,0,0};
        if (hi < 2) {
            a0 = *(const short8*)(sW0 + t * 512 + p * 16 + hi * 8);
            a1 = *(const short8*)(sW0 + t * 512 + 256 + p * 16 + hi * 8);
        }
        f32x4 z = {0.f, 0.f, 0.f, 0.f};
        f32x4 c0 = __builtin_amdgcn_mfma_f32_16x16x32_bf16(a0, bF, z, 0, 0, 0);
        f32x4 c1 = __builtin_amdgcn_mfma_f32_16x16x32_bf16(a1, bF, z, 0, 0, 0);
        // c0[r] = out1[hi*4+r][p], c1[r] = out1[16+hi*4+r][p]

        if constexpr (PHASE == 0) {
            #pragma unroll
            for (int r = 0; r < 4; r++) {
                s1[r]     += c0[r]; s2[r]     += c0[r] * c0[r];
                s1[4 + r] += c1[r]; s2[4 + r] += c1[r] * c1[r];
            }
        } else {
            const bool vs = (sp >= 0);
            short8 bS;
            #pragma unroll
            for (int r = 0; r < 4; r++) {
                float x0 = a1r[r] * c0[r] + b1r[r];
                float x1 = a1R[r] * c1[r] + b1R[r];
                bS[r]     = f2bf(vs ? silu_f(x0) : 0.f);
                bS[4 + r] = f2bf(vs ? silu_f(x1) : 0.f);
            }
            short8 a2v = {0,0,0,0,0,0,0,0};
            if (p < 8) {
                short4 A = *(const short4*)(sW1 + t * 256 + p * 32 + hi * 4);
                short4 B = *(const short4*)(sW1 + t * 256 + p * 32 + 16 + hi * 4);
                a2v[0] = A.x; a2v[1] = A.y; a2v[2] = A.z; a2v[3] = A.w;
                a2v[4] = B.x; a2v[5] = B.y; a2v[6] = B.z; a2v[7] = B.w;
            }
            f32x4 c2 = __builtin_amdgcn_mfma_f32_16x16x32_bf16(a2v, bS, z, 0, 0, 0);
            if (hi < 2 && sp >= 0) {
                short4 s;
                s.x = f2bf(c2[0]); s.y = f2bf(c2[1]); s.z = f2bf(c2[2]); s.w = f2bf(c2[3]);
                *(short4*)(o2b + (size_t)(base + sp) * 8 + hi * 4) = s;
            }
            #pragma unroll
            for (int r = 0; r < 4; r++) { s1[r] += c2[r]; s2[r] += c2[r] * c2[r]; }
        }
    }

    // ---- reduce over pair columns p ----
    constexpr int NC = (PHASE == 0) ? 8 : 4;
    #pragma unroll
    for (int c = 0; c < NC; c++) {
        float v1 = s1[c], v2 = s2[c];
        v1 += __shfl_xor(v1, 1, 64); v2 += __shfl_xor(v2, 1, 64);
        v1 += __shfl_xor(v1, 2, 64); v2 += __shfl_xor(v2, 2, 64);
        v1 += __shfl_xor(v1, 4, 64); v2 += __shfl_xor(v2, 4, 64);
        v1 += __shfl_xor(v1, 8, 64); v2 += __shfl_xor(v2, 8, 64);
        s1[c] = v1; s2[c] = v2;
    }
    if constexpr (PHASE == 0) {
        if (p == 0) {
            #pragma unroll
            for (int r = 0; r < 4; r++) {
                rS[wave][hi * 4 + r]      = s1[r];     rQ[wave][hi * 4 + r]      = s2[r];
                rS[wave][16 + hi * 4 + r] = s1[4 + r]; rQ[wave][16 + hi * 4 + r] = s2[4 + r];
            }
        }
        __syncthreads();
        if (tid < 32) {
            float a = 0.f, b = 0.f;
            #pragma unroll
            for (int w = 0; w < 8; w++) { a += rS[w][tid]; b += rQ[w][tid]; }
            partial[bid * 64 + tid]      = a;
            partial[bid * 64 + 32 + tid] = b;
        }
    } else {
        if (p == 0 && hi < 2) {
            #pragma unroll
            for (int r = 0; r < 4; r++) {
                rS[wave][hi * 4 + r] = s1[r];
                rQ[wave][hi * 4 + r] = s2[r];
            }
        }
        __syncthreads();
        if (tid < 8) {
            float a = 0.f, b = 0.f;
            #pragma unroll
            for (int w = 0; w < 8; w++) { a += rS[w][tid]; b += rQ[w][tid]; }
            partial[bid * 16 + tid]     = a;
            partial[bid * 16 + 8 + tid] = b;
        }
    }
}

// ---- fold BN1 stats into per-channel affine ----
template<int NS, int JW, int NB>
__global__ __launch_bounds__(1024)
void nep_finalize(const float* __restrict__ partial,
                  const float* __restrict__ gamma,
                  const float* __restrict__ beta,
                  const int* __restrict__ norm,
                  float* __restrict__ ab)
{
    __shared__ float ssum[JW][NS];
    __shared__ float ssq[JW][NS];
    const int c = threadIdx.x & (NS - 1);
    const int j = threadIdx.x / NS;
    float s = 0.f, q = 0.f;
    for (int blk = j; blk < NB; blk += JW) {
        s += partial[blk * (2 * NS) + c];
        q += partial[blk * (2 * NS) + NS + c];
    }
    ssum[j][c] = s; ssq[j][c] = q;
    __syncthreads();
    if (threadIdx.x < NS) {
        float st = 0.f, qt = 0.f;
        #pragma unroll
        for (int jj = 0; jj < JW; jj++) { st += ssum[jj][c]; qt += ssq[jj][c]; }
        const float invE = 1.0f / (float)E_TOTAL;
        float mean = st * invE;
        float var  = qt * invE - mean * mean;
        float inv  = rsqrtf(var + 1e-5f);
        float a, b;
        if (*norm) { a = gamma[c] * inv; b = beta[c] - mean * a; }
        else       { a = 1.f; b = 0.f; }
        ab[c] = a;
        ab[NS + c] = b;
    }
}

// ---- fused BN2 finalize + streaming epilogue ----
// Each block redundantly folds p2 (NBLK*16 floats, L2-broadcast), then applies
// out = silu(a2*o2 + b2) reading bf16 o2b, writing fp32 out.
__global__ __launch_bounds__(256)
void nep_bn2f(const short* __restrict__ o2b, const float* __restrict__ p2,
              const float* __restrict__ gamma, const float* __restrict__ beta,
              const int* __restrict__ norm, float* __restrict__ out)
{
    __shared__ float ssum[16][16];
    __shared__ float sA[8], sB[8];
    const int tid = threadIdx.x;
    {
        const int cc = tid & 15;
        const int j  = tid >> 4;
        float s = 0.f;
        for (int blk = j; blk < NBLK; blk += 16) s += p2[blk * 16 + cc];
        ssum[j][cc] = s;
    }
    __syncthreads();
    if (tid < 16) {
        float t = 0.f;
        #pragma unroll
        for (int jj = 0; jj < 16; jj++) t += ssum[jj][tid];
        ssum[0][tid] = t;
    }
    __syncthreads();
    if (tid < 8) {
        const float invE = 1.0f / (float)E_TOTAL;
        float mean = ssum[0][tid] * invE;
        float var  = ssum[0][8 + tid] * invE - mean * mean;
        float inv  = rsqrtf(var + 1e-5f);
        float a, b;
        if (*norm) { a = gamma[tid] * inv; b = beta[tid] - mean * a; }
        else       { a = 1.f; b = 0.f; }
        sA[tid] = a; sB[tid] = b;
    }
    __syncthreads();
    float a0 = sA[0], a1 = sA[1], a2 = sA[2], a3 = sA[3];
    float a4 = sA[4], a5 = sA[5], a6 = sA[6], a7 = sA[7];
    float b0 = sB[0], b1 = sB[1], b2 = sB[2], b3 = sB[3];
    float b4 = sB[4], b5 = sB[5], b6 = sB[6], b7 = sB[7];
    #pragma unroll
    for (int r = 0; r < 2; r++) {
        const int e = blockIdx.x * 256 + tid + r * (NBLK * 256);
        short8 v = *(const short8*)(o2b + (size_t)e * 8);
        float4 o0, o1;
        o0.x = silu_f(a0 * bf2f(v[0]) + b0);
        o0.y = silu_f(a1 * bf2f(v[1]) + b1);
        o0.z = silu_f(a2 * bf2f(v[2]) + b2);
        o0.w = silu_f(a3 * bf2f(v[3]) + b3);
        o1.x = silu_f(a4 * bf2f(v[4]) + b4);
        o1.y = silu_f(a5 * bf2f(v[5]) + b5);
        o1.z = silu_f(a6 * bf2f(v[6]) + b6);
        o1.w = silu_f(a7 * bf2f(v[7]) + b7);
        *(float4*)(out + (size_t)e * 8)     = o0;
        *(float4*)(out + (size_t)e * 8 + 4) = o1;
    }
}

extern "C" void kernel_launch(void* const* d_in, const int* in_sizes, int n_in,
                              void* d_out, int out_size, void* d_ws, size_t ws_size,
                              hipStream_t stream)
{
    const int*   ij   = (const int*)d_in[0];
    const float* fn   = (const float*)d_in[1];
    const float* W0   = (const float*)d_in[2];
    const float* W1   = (const float*)d_in[3];
    const float* g1   = (const float*)d_in[4];
    const float* b1   = (const float*)d_in[5];
    const float* g2   = (const float*)d_in[6];
    const float* b2   = (const float*)d_in[7];
    const int*   norm = (const int*)d_in[8];
    float* out = (float*)d_out;

    float* p1  = (float*)d_ws;        // 512*64
    float* p2  = p1 + NBLK * 64;      // 512*16
    float* ab1 = p2 + NBLK * 16;      // 64
    short* o2b = (short*)(ab1 + 64);  // E*8 bf16 (4 MB)

    nep_main<0><<<NBLK, TPB, 0, stream>>>(ij, fn, W0, W1, nullptr, p1, nullptr);
    nep_finalize<32, 16, NBLK><<<1, 512, 0, stream>>>(p1, g1, b1, norm, ab1);
    nep_main<1><<<NBLK, TPB, 0, stream>>>(ij, fn, W0, W1, ab1, p2, o2b);
    nep_bn2f<<<NBLK, 256, 0, stream>>>(o2b, p2, g2, b2, norm, out);
}